// Round 6
// baseline (305.142 us; speedup 1.0000x reference)
//
#include <hip/hip_runtime.h>
#include <math.h>

// Problem constants: N=200 LSTMs, B=100, T=256, D=5 (io), H=20 (units)
constexpr int NL = 200;
constexpr int B  = 100;
constexpr int T  = 256;
constexpr int D  = 5;
constexpr int H  = 20;
constexpr int NW = 7;      // waves (16-batch groups) per LSTM; 7*16=112 >= 100
constexpr int KP = 40;     // bcol row pitch in bf16 (80 B)

// k-axis layout of the per-batch data column (K=32):
//   k 0..23  = h region, k = g4*6 + Mt  (hh = Mt*4 + g4; Mt==5 -> always 0)
//   k 24..28 = x_t[0..4]  (one aligned 16B store, k24..31)
//   k 29..31 = 0
constexpr int KX = 24;

typedef float  f32x4  __attribute__((ext_vector_type(4)));
typedef short  bf16x8 __attribute__((ext_vector_type(8)));

__device__ __forceinline__ float rcpf(float x) { return __builtin_amdgcn_rcpf(x); }

#if __has_builtin(__builtin_amdgcn_exp2f)
__device__ __forceinline__ float exp2fast(float x) { return __builtin_amdgcn_exp2f(x); }
#else
__device__ __forceinline__ float exp2fast(float x) { return __expf(x * 0.6931471805599453f); }
#endif

// fp32 -> bf16 bits, round-to-nearest-even
__device__ __forceinline__ unsigned short f2bf(float f) {
    union { float f; unsigned u; } v; v.f = f;
    unsigned r = v.u + 0x7fffu + ((v.u >> 16) & 1u);
    return (unsigned short)(r >> 16);
}
__device__ __forceinline__ unsigned pk2bf(float lo, float hi) {
    return (unsigned)f2bf(lo) | ((unsigned)f2bf(hi) << 16);
}

constexpr float NLOG2E = -1.4426950408889634f;
constexpr float TLOG2E = 2.8853900817779268f;   // 2*log2(e)

__global__ __launch_bounds__(256) void init_out_kernel(const float* __restrict__ dense_b,
                                                       float* __restrict__ out, int n) {
    int i = blockIdx.x * 256 + threadIdx.x;
    if (i < n) out[i] = dense_b[i % D];
}

// One 64-thread block (one wave) per (lstm n, 16-batch group w).
// Transposed gate GEMM per timestep with v_mfma_f32_16x16x32_bf16:
//   A[80 x 32] = gate weights (row r = 4*hh + gate), cols per k-layout above,
//                rows pre-scaled by -log2e (i,f,o) / +2log2e (g) [registers]
//   B[32 x 16] = per-batch data columns [LDS bf16]; C-init = scaled bias.
// C/D layout (HW-verified): col = lane&15 (batch), row = (lane>>4)*4 + reg
//   => lane's 4 accs = {i,f,g,o} of (b = 16w+(lane&15), hh = 4*Mt + (lane>>4)).
// A/B share the same (k-group, j) -> k bijection, so any bijection is correct.
template<bool USE_WS>
__global__ __attribute__((amdgpu_flat_work_group_size(64, 64),
                          amdgpu_waves_per_eu(1, 2)))
void lstm_mfma_kernel(
    const float* __restrict__ x,    // [B][T][D]
    const float* __restrict__ Wg,   // [N][D][4H]
    const float* __restrict__ Ug,   // [N][H][4H]
    const float* __restrict__ bg,   // [N][4H]
    const float* __restrict__ dWg,  // [N*H][D]
    float* __restrict__ pw,         // [N][T][D][B] partials (USE_WS)
    float* __restrict__ out)        // [B][T][D] (atomic fallback)
{
    const int blk = blockIdx.x;            // 0..1399
    const int n   = blk / NW;
    const int w   = blk % NW;
    const int l   = threadIdx.x;           // 0..63
    const int c16 = l & 15;
    const int g4  = l >> 4;                // k-group / row-group

    __shared__ __align__(16) short bcol[16][KP];   // [local batch][k], bf16 bits

    // zero-init (covers pad slots permanently; h region for t=0)
    for (int i = l; i < 16 * KP / 2; i += 64) ((int*)bcol)[i] = 0;
    __builtin_amdgcn_wave_barrier();

    // ---- A fragments (gate weights), built once with k = 8*g4 + j ----
    const float* Un = Ug + (size_t)n * H * 4 * H;
    const float* Wn = Wg + (size_t)n * D * 4 * H;
    const float* bn = bg + (size_t)n * 4 * H;

    const int gateA = c16 & 3;                     // A-row gate for this lane
    const float sA  = (gateA == 2) ? TLOG2E : NLOG2E;
    bf16x8 afrag[5];
    #pragma unroll
    for (int Mt = 0; Mt < 5; ++Mt) {
        const int hhA = Mt * 4 + (c16 >> 2);       // A-row hh for this lane
        const int col = gateA * H + hhA;           // column in [*,4H] weight mats
        #pragma unroll
        for (int j = 0; j < 8; ++j) {
            const int k = 8 * g4 + j;
            float v = 0.0f;
            if (k < KX) {                          // h region: k = gg*6 + mt
                const int mt = k % 6, gg = k / 6;
                if (mt < 5) v = Un[(mt * 4 + gg) * 4 * H + col];
            } else if (k < KX + D) {
                v = Wn[(k - KX) * 4 * H + col];
            }
            afrag[Mt][j] = (short)f2bf(sA * v);
        }
    }

    // ---- C-init = scaled bias; cell state; dense weights (lane's hh set) ----
    f32x4 biasv[5];
    float cst[5];
    float dwr[5][5];
    #pragma unroll
    for (int Mt = 0; Mt < 5; ++Mt) {
        const int hh = Mt * 4 + g4;
        biasv[Mt][0] = NLOG2E * bn[0 * H + hh];
        biasv[Mt][1] = NLOG2E * bn[1 * H + hh];
        biasv[Mt][2] = TLOG2E * bn[2 * H + hh];
        biasv[Mt][3] = NLOG2E * bn[3 * H + hh];
        cst[Mt] = 0.0f;
        #pragma unroll
        for (int d = 0; d < D; ++d) dwr[Mt][d] = dWg[(n * H + hh) * D + d];
    }

    const int  bgl    = w * 16 + c16;              // global batch of this lane-col
    const bool bvalid = bgl < B;
    const float* xp   = x + (size_t)(bvalid ? bgl : 0) * T * D;
    float* pwn = USE_WS ? (pw + (size_t)n * T * (D * B))
                        : (out + ((size_t)bgl * T) * D);

    // x(0) preloaded into registers
    float xcur[D], xnext[D];
    #pragma unroll
    for (int d = 0; d < D; ++d) xcur[d] = xp[d];

    for (int t = 0; t < T; ++t) {
        // stage x(t) from registers into k24..31 (lanes 0..15)
        if (l < 16) {
            bf16x8 xb;
            #pragma unroll
            for (int d = 0; d < D; ++d) xb[d] = (short)f2bf(xcur[d]);
            xb[5] = 0; xb[6] = 0; xb[7] = 0;
            *(bf16x8*)&bcol[c16][KX] = xb;         // 16B aligned ds_write
        }
        // issue x(t+1) loads now; they complete under MFMA + activations
        {
            const float* xnp = xp + (size_t)((t + 1 < T) ? t + 1 : t) * D;
            #pragma unroll
            for (int d = 0; d < D; ++d) xnext[d] = xnp[d];
        }
        __builtin_amdgcn_wave_barrier();           // order writes before read

        const bf16x8 bfrag = *(const bf16x8*)&bcol[c16][8 * g4];  // ds_read_b128

        f32x4 acc[5];
        #pragma unroll
        for (int Mt = 0; Mt < 5; ++Mt)
            acc[Mt] = __builtin_amdgcn_mfma_f32_16x16x32_bf16(afrag[Mt], bfrag,
                                                              biasv[Mt], 0, 0, 0);
        float hof[5];
        #pragma unroll
        for (int Mt = 0; Mt < 5; ++Mt) {
            // acc = {-z_i, -z_f, 2*z_g, -z_o} * log2e  (+scaled bias)
            const float iv = rcpf(1.0f + exp2fast(acc[Mt][0]));
            const float fv = rcpf(1.0f + exp2fast(acc[Mt][1]));
            const float gv = fmaf(-2.0f, rcpf(exp2fast(acc[Mt][2]) + 1.0f), 1.0f);
            const float ov = rcpf(1.0f + exp2fast(acc[Mt][3]));
            const float cv = fmaf(fv, cst[Mt], iv * gv);
            cst[Mt] = cv;
            const float th = fmaf(-2.0f, rcpf(exp2fast(TLOG2E * cv) + 1.0f), 1.0f);
            hof[Mt] = ov * th;
        }
        // h for next step: 3 contiguous dword writes at k = g4*6 .. g4*6+5
        {
            unsigned* hw = (unsigned*)&bcol[c16][g4 * 6];
            hw[0] = pk2bf(hof[0], hof[1]);
            hw[1] = pk2bf(hof[2], hof[3]);
            hw[2] = pk2bf(hof[4], 0.0f);
        }

        // fused dense: out_part(b,d) = sum_hh h(b,hh) * dW[n*H+hh][d]
        float sd[D];
        #pragma unroll
        for (int d = 0; d < D; ++d) {
            float s_ = hof[0] * dwr[0][d];
            #pragma unroll
            for (int Mt = 1; Mt < 5; ++Mt) s_ = fmaf(hof[Mt], dwr[Mt][d], s_);
            s_ += __shfl_xor(s_, 16);
            s_ += __shfl_xor(s_, 32);
            sd[d] = s_;
        }
        if (l < 16 && bvalid) {
            if (USE_WS) {
                #pragma unroll
                for (int d = 0; d < D; ++d)
                    pwn[(size_t)t * (D * B) + d * B + bgl] = sd[d];  // coalesced
            } else {
                #pragma unroll
                for (int d = 0; d < D; ++d)
                    atomicAdd(&pwn[(size_t)t * D + d], sd[d]);
            }
        }
        #pragma unroll
        for (int d = 0; d < D; ++d) xcur[d] = xnext[d];
    }
}

// out[b][t][d] = dense_b[d] + sum_n pw[n][t][d][b]  (coalesced reads)
__global__ __launch_bounds__(512) void reduce_kernel(
    const float* __restrict__ pw, const float* __restrict__ dense_b,
    float* __restrict__ out)
{
    const int t    = blockIdx.x;
    const int flat = threadIdx.x;              // d*B + b, 0..499
    if (flat >= B * D) return;
    const int d = flat / B;
    const int b = flat % B;
    const float* p = pw + (size_t)t * (D * B) + flat;
    constexpr size_t stride = (size_t)T * D * B;
    float a0 = 0.0f, a1 = 0.0f;
    #pragma unroll 10
    for (int n = 0; n < NL; n += 2) {
        a0 += p[(size_t)n * stride];
        a1 += p[(size_t)(n + 1) * stride];
    }
    out[((size_t)b * T + t) * D + d] = a0 + a1 + dense_b[d];
}

extern "C" void kernel_launch(void* const* d_in, const int* in_sizes, int n_in,
                              void* d_out, int out_size, void* d_ws, size_t ws_size,
                              hipStream_t stream) {
    const float* x   = (const float*)d_in[0];
    const float* Wg  = (const float*)d_in[1];
    const float* Ug  = (const float*)d_in[2];
    const float* bg  = (const float*)d_in[3];
    const float* dWg = (const float*)d_in[4];
    const float* dbv = (const float*)d_in[5];
    float* out = (float*)d_out;

    const size_t need = (size_t)NL * T * D * B * sizeof(float);   // 102.4 MB
    if (ws_size >= need) {
        float* pw = (float*)d_ws;
        lstm_mfma_kernel<true><<<NL * NW, 64, 0, stream>>>(x, Wg, Ug, bg, dWg, pw, out);
        reduce_kernel<<<T, 512, 0, stream>>>(pw, dbv, out);
    } else {
        init_out_kernel<<<(out_size + 255) / 256, 256, 0, stream>>>(dbv, out, out_size);
        lstm_mfma_kernel<false><<<NL * NW, 64, 0, stream>>>(x, Wg, Ug, bg, dWg, nullptr, out);
    }
}

// Round 7
// 294.196 us; speedup vs baseline: 1.0372x; 1.0372x over previous
//
#include <hip/hip_runtime.h>
#include <math.h>

// Problem constants: N=200 LSTMs, B=100, T=256, D=5 (io), H=20 (units)
constexpr int NL = 200;
constexpr int B  = 100;
constexpr int T  = 256;
constexpr int D  = 5;
constexpr int H  = 20;
constexpr int NW = 7;      // waves (16-batch groups) per LSTM; 7*16=112 >= 100
constexpr int KP = 40;     // bcol row pitch in bf16 (80 B)

// k-axis layout of the per-batch data column (K=32):
//   k 0..23  = h region, k = g*6 + mt  (hh = mt*4 + g; mt==5 -> always 0)
//   k 24..28 = x_t[0..4]   (one aligned 16B store per step, k24..31)
//   k 30     = 1.0 (bias slot; rewritten each step as part of the x store)
//   k 29,31  = 0
constexpr int KX = 24;

typedef float  f32x4  __attribute__((ext_vector_type(4)));
typedef short  bf16x8 __attribute__((ext_vector_type(8)));

__device__ __forceinline__ float rcpf(float x) { return __builtin_amdgcn_rcpf(x); }

#if __has_builtin(__builtin_amdgcn_exp2f)
__device__ __forceinline__ float exp2fast(float x) { return __builtin_amdgcn_exp2f(x); }
#else
__device__ __forceinline__ float exp2fast(float x) { return __expf(x * 0.6931471805599453f); }
#endif

// fp32 -> bf16 bits, round-to-nearest-even
__device__ __forceinline__ unsigned short f2bf(float f) {
    union { float f; unsigned u; } v; v.f = f;
    unsigned r = v.u + 0x7fffu + ((v.u >> 16) & 1u);
    return (unsigned short)(r >> 16);
}
__device__ __forceinline__ unsigned pk2bf(float lo, float hi) {
    return (unsigned)f2bf(lo) | ((unsigned)f2bf(hi) << 16);
}

constexpr float NLOG2E = -1.4426950408889634f;
constexpr float TLOG2E = 2.8853900817779268f;   // 2*log2(e)

__global__ __launch_bounds__(256) void init_out_kernel(const float* __restrict__ dense_b,
                                                       float* __restrict__ out, int n) {
    int i = blockIdx.x * 256 + threadIdx.x;
    if (i < n) out[i] = dense_b[i % D];
}

// One 64-thread block (one wave) per (lstm n, 16-batch group w).
// Per iteration: ONE ds_read_b128 (bfrag) feeds SIX mfma_f32_16x16x32_bf16:
//   5 recurrence tiles (A = gate weights, 80x32, bias folded into k=30 col)
//   1 dense tile      (A = dense_W^T, rows 0..4 = d, zeros outside h region)
// C-inits are literal zero. Lane (c16,g4): recurrence accs = 4 gates of
// (hh = 4*Mt + g4, b = 16w + c16); dense accs = rows 4*g4+reg = d, col = b.
// Dense is pipelined one step behind (uses h(t-1) present in bcol); loop runs
// T+1 iterations, iteration T does only the final dense.
template<bool USE_WS>
__global__ __attribute__((amdgpu_flat_work_group_size(64, 64),
                          amdgpu_waves_per_eu(1, 2)))
void lstm_mfma_kernel(
    const float* __restrict__ x,    // [B][T][D]
    const float* __restrict__ Wg,   // [N][D][4H]
    const float* __restrict__ Ug,   // [N][H][4H]
    const float* __restrict__ bg,   // [N][4H]
    const float* __restrict__ dWg,  // [N*H][D]
    float* __restrict__ pw,         // [N][T][D][B] partials (USE_WS)
    float* __restrict__ out)        // [B][T][D] (atomic fallback)
{
    const int blk = blockIdx.x;            // 0..1399
    const int n   = blk / NW;
    const int w   = blk % NW;
    const int l   = threadIdx.x;           // 0..63
    const int c16 = l & 15;
    const int g4  = l >> 4;                // k-group / row-group

    __shared__ __align__(16) short bcol[16][KP];   // [local batch][k], bf16 bits

    // zero-init (pad slots stay 0 forever; h region = h(-1) = 0)
    for (int i = l; i < 16 * KP / 2; i += 64) ((int*)bcol)[i] = 0;
    __builtin_amdgcn_wave_barrier();

    const float* Un = Ug  + (size_t)n * H * 4 * H;
    const float* Wn = Wg  + (size_t)n * D * 4 * H;
    const float* bn = bg  + (size_t)n * 4 * H;
    const float* dn = dWg + (size_t)n * H * D;

    // ---- A fragments, built once with k = 8*g4 + j ----
    // recurrence: lane's A-row (within tile Mt) = c16; global row = 16Mt + c16
    //   = 4*hh + gate with hh = 4Mt + (c16>>2), gate = c16&3.
    const int gateA = c16 & 3;
    const int hA4   = c16 >> 2;
    const float sA  = (gateA == 2) ? TLOG2E : NLOG2E;
    bf16x8 afrag[5];
    #pragma unroll
    for (int Mt = 0; Mt < 5; ++Mt) {
        const int col = gateA * H + (Mt * 4 + hA4);   // column in [*,4H] weights
        #pragma unroll
        for (int j = 0; j < 8; ++j) {
            const int k = 8 * g4 + j;
            float v = 0.0f;
            if (k < KX) {                              // h region: k = g*6 + mt
                const int mt = k % 6, gg = k / 6;
                if (mt < 5) v = Un[(mt * 4 + gg) * 4 * H + col];
            } else if (k < KX + D) {                   // x region
                v = Wn[(k - KX) * 4 * H + col];
            } else if (k == 30) {                      // bias slot
                v = bn[col];
            }
            afrag[Mt][j] = (short)f2bf(sA * v);
        }
    }
    // dense: lane's A-row = c16 (rows 0..4 = d, rest zero); h region only
    bf16x8 afrag_d;
    #pragma unroll
    for (int j = 0; j < 8; ++j) {
        const int k = 8 * g4 + j;
        float v = 0.0f;
        if (c16 < D && k < KX) {
            const int mt = k % 6, gg = k / 6;
            if (mt < 5) v = dn[(mt * 4 + gg) * D + c16];
        }
        afrag_d[j] = (short)f2bf(v);
    }

    const int  bgl    = w * 16 + c16;              // global batch of this lane-col
    const bool bvalid = bgl < B;
    const float* xp   = x + (size_t)(bvalid ? bgl : 0) * T * D;
    float* pwn = USE_WS ? (pw + (size_t)n * T * (D * B))
                        : (out + ((size_t)bgl * T) * D);

    // prologue: stage x(0); preload x(1) into regs
    float xn[D];
    if (l < 16) {
        bf16x8 xb;
        #pragma unroll
        for (int d = 0; d < D; ++d) xb[d] = (short)f2bf(xp[d]);
        xb[5] = 0; xb[6] = (short)0x3F80; xb[7] = 0;      // bias slot = 1.0
        *(bf16x8*)&bcol[c16][KX] = xb;
        const float* x1 = xp + (size_t)((T > 1) ? 1 : 0) * D;
        #pragma unroll
        for (int d = 0; d < D; ++d) xn[d] = x1[d];
    }
    __builtin_amdgcn_wave_barrier();

    float cst[5] = {0.0f, 0.0f, 0.0f, 0.0f, 0.0f};
    const f32x4 zero4 = {0.0f, 0.0f, 0.0f, 0.0f};

    for (int t = 0; t <= T; ++t) {
        // bcol holds h(t-1) and x(t)
        const bf16x8 bfrag = *(const bf16x8*)&bcol[c16][8 * g4];  // ds_read_b128

        // ---- dense for step t-1 (h(t-1)) ----
        const f32x4 accd = __builtin_amdgcn_mfma_f32_16x16x32_bf16(afrag_d, bfrag,
                                                                   zero4, 0, 0, 0);
        if (t > 0 && bvalid) {
            #pragma unroll
            for (int reg = 0; reg < 4; ++reg) {
                const int d = g4 * 4 + reg;               // output row = d
                if (d < D) {
                    if (USE_WS)
                        pwn[(size_t)(t - 1) * (D * B) + d * B + bgl] = accd[reg];
                    else
                        atomicAdd(&pwn[(size_t)(t - 1) * D + d], accd[reg]);
                }
            }
        }
        if (t == T) break;

        // stage x(t+1) (regs -> LDS; read above already consumed x(t)),
        // then issue the global load for x(t+2)
        if (l < 16) {
            bf16x8 xb;
            #pragma unroll
            for (int d = 0; d < D; ++d) xb[d] = (short)f2bf(xn[d]);
            xb[5] = 0; xb[6] = (short)0x3F80; xb[7] = 0;
            *(bf16x8*)&bcol[c16][KX] = xb;
            const float* x2 = xp + (size_t)((t + 2 < T) ? t + 2 : T - 1) * D;
            #pragma unroll
            for (int d = 0; d < D; ++d) xn[d] = x2[d];
        }

        // ---- recurrence: 5 MFMA tiles + activations ----
        f32x4 acc[5];
        #pragma unroll
        for (int Mt = 0; Mt < 5; ++Mt)
            acc[Mt] = __builtin_amdgcn_mfma_f32_16x16x32_bf16(afrag[Mt], bfrag,
                                                              zero4, 0, 0, 0);
        float hof[5];
        #pragma unroll
        for (int Mt = 0; Mt < 5; ++Mt) {
            // acc = {-z_i, -z_f, 2*z_g, -z_o} * log2e (bias included via k=30)
            const float iv = rcpf(1.0f + exp2fast(acc[Mt][0]));
            const float fv = rcpf(1.0f + exp2fast(acc[Mt][1]));
            const float gv = fmaf(-2.0f, rcpf(exp2fast(acc[Mt][2]) + 1.0f), 1.0f);
            const float ov = rcpf(1.0f + exp2fast(acc[Mt][3]));
            const float cv = fmaf(fv, cst[Mt], iv * gv);
            cst[Mt] = cv;
            const float th = fmaf(-2.0f, rcpf(exp2fast(TLOG2E * cv) + 1.0f), 1.0f);
            hof[Mt] = ov * th;
        }
        // h(t) for next step: 3 contiguous dword writes at k = g4*6 .. g4*6+5
        {
            unsigned* hw = (unsigned*)&bcol[c16][g4 * 6];
            hw[0] = pk2bf(hof[0], hof[1]);
            hw[1] = pk2bf(hof[2], hof[3]);
            hw[2] = pk2bf(hof[4], 0.0f);
        }
        __builtin_amdgcn_wave_barrier();
    }
}

// out[b][t][d] = dense_b[d] + sum_n pw[n][t][d][b]  (coalesced reads)
__global__ __launch_bounds__(512) void reduce_kernel(
    const float* __restrict__ pw, const float* __restrict__ dense_b,
    float* __restrict__ out)
{
    const int t    = blockIdx.x;
    const int flat = threadIdx.x;              // d*B + b, 0..499
    if (flat >= B * D) return;
    const int d = flat / B;
    const int b = flat % B;
    const float* p = pw + (size_t)t * (D * B) + flat;
    constexpr size_t stride = (size_t)T * D * B;
    float a0 = 0.0f, a1 = 0.0f;
    #pragma unroll 10
    for (int n = 0; n < NL; n += 2) {
        a0 += p[(size_t)n * stride];
        a1 += p[(size_t)(n + 1) * stride];
    }
    out[((size_t)b * T + t) * D + d] = a0 + a1 + dense_b[d];
}

extern "C" void kernel_launch(void* const* d_in, const int* in_sizes, int n_in,
                              void* d_out, int out_size, void* d_ws, size_t ws_size,
                              hipStream_t stream) {
    const float* x   = (const float*)d_in[0];
    const float* Wg  = (const float*)d_in[1];
    const float* Ug  = (const float*)d_in[2];
    const float* bg  = (const float*)d_in[3];
    const float* dWg = (const float*)d_in[4];
    const float* dbv = (const float*)d_in[5];
    float* out = (float*)d_out;

    const size_t need = (size_t)NL * T * D * B * sizeof(float);   // 102.4 MB
    if (ws_size >= need) {
        float* pw = (float*)d_ws;
        lstm_mfma_kernel<true><<<NL * NW, 64, 0, stream>>>(x, Wg, Ug, bg, dWg, pw, out);
        reduce_kernel<<<T, 512, 0, stream>>>(pw, dbv, out);
    } else {
        init_out_kernel<<<(out_size + 255) / 256, 256, 0, stream>>>(dbv, out, out_size);
        lstm_mfma_kernel<false><<<NL * NW, 64, 0, stream>>>(x, Wg, Ug, bg, dWg, nullptr, out);
    }
}

// Round 9
// 230.171 us; speedup vs baseline: 1.3257x; 1.2782x over previous
//
#include <hip/hip_runtime.h>
#include <math.h>

// Problem constants: N=200 LSTMs, B=100, T=256, D=5 (io), H=20 (units)
constexpr int NL = 200;
constexpr int B  = 100;
constexpr int T  = 256;
constexpr int D  = 5;
constexpr int H  = 20;
constexpr int NW = 7;      // 16-batch groups per LSTM; 7*16=112 >= 100
constexpr int KP = 40;     // bcol row pitch in bf16 (80 B)
constexpr int NWAVE = 5;   // wave m computes recurrence tile Mt=m
constexpr int BLKT  = 64 * NWAVE;   // 320 threads

// k-axis layout of the per-batch data column (K=32):
//   k 0..23  = h region, k = g*6 + mt  (hh = mt*4 + g; mt==5 -> always 0)
//   k 24..28 = x_t[0..4]   (one aligned 16B store per step, k24..31)
//   k 30     = 1.0 (bias slot), k 29,31 = 0
constexpr int KX = 24;

typedef float  f32x4  __attribute__((ext_vector_type(4)));
typedef short  bf16x8 __attribute__((ext_vector_type(8)));

__device__ __forceinline__ float rcpf(float x) { return __builtin_amdgcn_rcpf(x); }

#if __has_builtin(__builtin_amdgcn_exp2f)
__device__ __forceinline__ float exp2fast(float x) { return __builtin_amdgcn_exp2f(x); }
#else
__device__ __forceinline__ float exp2fast(float x) { return __expf(x * 0.6931471805599453f); }
#endif

// fp32 -> bf16 bits, round-to-nearest-even
__device__ __forceinline__ unsigned short f2bf(float f) {
    union { float f; unsigned u; } v; v.f = f;
    unsigned r = v.u + 0x7fffu + ((v.u >> 16) & 1u);
    return (unsigned short)(r >> 16);
}

constexpr float NLOG2E = -1.4426950408889634f;
constexpr float TLOG2E = 2.8853900817779268f;   // 2*log2(e)

__global__ __launch_bounds__(256) void init_out_kernel(const float* __restrict__ dense_b,
                                                       float* __restrict__ out, int n) {
    int i = blockIdx.x * 256 + threadIdx.x;
    if (i < n) out[i] = dense_b[i % D];
}

// One block per (lstm n, 16-batch group w); 5 waves per block.
// Wave m: ONE mfma_f32_16x16x32_bf16 (gate tile Mt=m; bias folded into k=30
// column, scale -log2e / +2log2e folded into A) + ONE activation chain per
// step; lane (c16,g4) owns (hh = 4m+g4, b = 16w+c16) and writes ONE bf16 h.
// Wave 1 extra: dense MFMA (A = dense_W^T rows d=0..4) pipelined one step
// behind. Wave 0 lanes<16 extra: stage x into the other buffer.
// bcol double-buffered; ONE __syncthreads per step.
template<bool USE_WS>
__global__ __attribute__((amdgpu_flat_work_group_size(BLKT, BLKT)))
void lstm_mfma5_kernel(
    const float* __restrict__ x,    // [B][T][D]
    const float* __restrict__ Wg,   // [N][D][4H]
    const float* __restrict__ Ug,   // [N][H][4H]
    const float* __restrict__ bg,   // [N][4H]
    const float* __restrict__ dWg,  // [N*H][D]
    float* __restrict__ pw,         // [N][T][D][B] partials (USE_WS)
    float* __restrict__ out)        // [B][T][D] (atomic fallback)
{
    const int blk = blockIdx.x;            // 0..1399
    const int n   = blk / NW;
    const int w   = blk % NW;
    const int tid = threadIdx.x;
    const int wid = tid >> 6;              // 0..4 = Mt of this wave
    const int l   = tid & 63;
    const int c16 = l & 15;
    const int g4  = l >> 4;

    __shared__ __align__(16) short bcol[2][16][KP];   // double-buffered

    for (int i = tid; i < 2 * 16 * KP / 2; i += BLKT)
        ((int*)&bcol[0][0][0])[i] = 0;

    const float* Un = Ug  + (size_t)n * H * 4 * H;
    const float* Wn = Wg  + (size_t)n * D * 4 * H;
    const float* bn = bg  + (size_t)n * 4 * H;
    const float* dn = dWg + (size_t)n * H * D;

    // ---- recurrence A fragment for this wave (Mt = wid), k = 8*g4 + j ----
    const int gateA = c16 & 3;
    const int hA4   = c16 >> 2;
    const float sA  = (gateA == 2) ? TLOG2E : NLOG2E;
    const int colA  = gateA * H + (wid * 4 + hA4);   // column in [*,4H] weights
    bf16x8 afrag;
    #pragma unroll
    for (int j = 0; j < 8; ++j) {
        const int k = 8 * g4 + j;
        float v = 0.0f;
        if (k < KX) {                          // h region: k = g*6 + mt
            const int mt = k % 6, gg = k / 6;
            if (mt < 5) v = Un[(mt * 4 + gg) * 4 * H + colA];
        } else if (k < KX + D) {               // x region
            v = Wn[(k - KX) * 4 * H + colA];
        } else if (k == 30) {                  // bias slot
            v = bn[colA];
        }
        afrag[j] = (short)f2bf(sA * v);
    }
    // ---- dense A fragment (wave 1 only): rows 0..4 = d, h region only ----
    bf16x8 afrag_d = {};
    if (wid == 1) {
        #pragma unroll
        for (int j = 0; j < 8; ++j) {
            const int k = 8 * g4 + j;
            float v = 0.0f;
            if (c16 < D && k < KX) {
                const int mt = k % 6, gg = k / 6;
                if (mt < 5) v = dn[(mt * 4 + gg) * D + c16];
            }
            afrag_d[j] = (short)f2bf(v);
        }
    }

    const int  bgl    = w * 16 + c16;          // global batch of this lane-col
    const bool bvalid = bgl < B;
    const float* xp   = x + (size_t)(bvalid ? bgl : 0) * T * D;
    float* pwn = USE_WS ? (pw + (size_t)n * T * (D * B))
                        : (out + ((size_t)bgl * T) * D);

    __syncthreads();                            // zero-init visible

    // prologue: wave0 stages x(0) into buf 0; preloads x(1)
    float xn[D];
    if (wid == 0 && l < 16) {
        bf16x8 xb;
        #pragma unroll
        for (int d = 0; d < D; ++d) xb[d] = (short)f2bf(xp[d]);
        xb[5] = 0; xb[6] = (short)0x3F80; xb[7] = 0;      // bias = 1.0
        *(bf16x8*)&bcol[0][c16][KX] = xb;
        const float* x1 = xp + (size_t)((T > 1) ? 1 : 0) * D;
        #pragma unroll
        for (int d = 0; d < D; ++d) xn[d] = x1[d];
    }
    __syncthreads();

    float cst = 0.0f;
    const f32x4 zero4 = {0.0f, 0.0f, 0.0f, 0.0f};
    int p = 0;

    for (int t = 0; t < T; ++t) {
        // buf[p] holds h(t-1) and x(t)
        const bf16x8 bfrag = *(const bf16x8*)&bcol[p][c16][8 * g4];  // ds_read_b128

        if (wid == 1) {
            // dense for step t-1 (uses h(t-1) in bfrag)
            const f32x4 accd = __builtin_amdgcn_mfma_f32_16x16x32_bf16(
                afrag_d, bfrag, zero4, 0, 0, 0);
            if (t > 0 && bvalid) {
                #pragma unroll
                for (int reg = 0; reg < 4; ++reg) {
                    const int d = g4 * 4 + reg;            // output row = d
                    if (d < D) {
                        if (USE_WS)
                            pwn[(size_t)(t - 1) * (D * B) + d * B + bgl] = accd[reg];
                        else
                            atomicAdd(&pwn[(size_t)(t - 1) * D + d], accd[reg]);
                    }
                }
            }
        }

        // recurrence tile Mt = wid
        const f32x4 acc = __builtin_amdgcn_mfma_f32_16x16x32_bf16(
            afrag, bfrag, zero4, 0, 0, 0);
        // acc = {-z_i, -z_f, 2*z_g, -z_o} * log2e  (bias via k=30)
        const float iv = rcpf(1.0f + exp2fast(acc[0]));
        const float fv = rcpf(1.0f + exp2fast(acc[1]));
        const float gv = fmaf(-2.0f, rcpf(exp2fast(acc[2]) + 1.0f), 1.0f);
        const float ov = rcpf(1.0f + exp2fast(acc[3]));
        cst = fmaf(fv, cst, iv * gv);
        const float th = fmaf(-2.0f, rcpf(exp2fast(TLOG2E * cst) + 1.0f), 1.0f);
        const float hv = ov * th;

        // h(t): one bf16 store at k = g4*6 + wid into the other buffer
        bcol[p ^ 1][c16][g4 * 6 + wid] = (short)f2bf(hv);

        // wave0: stage x(t+1) into the other buffer; load x(t+2)
        if (wid == 0 && l < 16) {
            bf16x8 xb;
            #pragma unroll
            for (int d = 0; d < D; ++d) xb[d] = (short)f2bf(xn[d]);
            xb[5] = 0; xb[6] = (short)0x3F80; xb[7] = 0;
            *(bf16x8*)&bcol[p ^ 1][c16][KX] = xb;
            const float* x2 = xp + (size_t)((t + 2 < T) ? t + 2 : T - 1) * D;
            #pragma unroll
            for (int d = 0; d < D; ++d) xn[d] = x2[d];
        }

        __syncthreads();
        p ^= 1;
    }

    // final dense: buf[p] holds h(T-1)
    if (wid == 1) {
        const bf16x8 bfrag = *(const bf16x8*)&bcol[p][c16][8 * g4];
        const f32x4 accd = __builtin_amdgcn_mfma_f32_16x16x32_bf16(
            afrag_d, bfrag, zero4, 0, 0, 0);
        if (bvalid) {
            #pragma unroll
            for (int reg = 0; reg < 4; ++reg) {
                const int d = g4 * 4 + reg;
                if (d < D) {
                    if (USE_WS)
                        pwn[(size_t)(T - 1) * (D * B) + d * B + bgl] = accd[reg];
                    else
                        atomicAdd(&pwn[(size_t)(T - 1) * D + d], accd[reg]);
                }
            }
        }
    }
}

// out[b][t][d] = dense_b[d] + sum_n pw[n][t][d][b]  (coalesced reads)
__global__ __launch_bounds__(512) void reduce_kernel(
    const float* __restrict__ pw, const float* __restrict__ dense_b,
    float* __restrict__ out)
{
    const int t    = blockIdx.x;
    const int flat = threadIdx.x;              // d*B + b, 0..499
    if (flat >= B * D) return;
    const int d = flat / B;
    const int b = flat % B;
    const float* p = pw + (size_t)t * (D * B) + flat;
    constexpr size_t stride = (size_t)T * D * B;
    float a0 = 0.0f, a1 = 0.0f;
    #pragma unroll 10
    for (int n = 0; n < NL; n += 2) {
        a0 += p[(size_t)n * stride];
        a1 += p[(size_t)(n + 1) * stride];
    }
    out[((size_t)b * T + t) * D + d] = a0 + a1 + dense_b[d];
}

extern "C" void kernel_launch(void* const* d_in, const int* in_sizes, int n_in,
                              void* d_out, int out_size, void* d_ws, size_t ws_size,
                              hipStream_t stream) {
    const float* x   = (const float*)d_in[0];
    const float* Wg  = (const float*)d_in[1];
    const float* Ug  = (const float*)d_in[2];
    const float* bg  = (const float*)d_in[3];
    const float* dWg = (const float*)d_in[4];
    const float* dbv = (const float*)d_in[5];
    float* out = (float*)d_out;

    const size_t need = (size_t)NL * T * D * B * sizeof(float);   // 102.4 MB
    if (ws_size >= need) {
        float* pw = (float*)d_ws;
        lstm_mfma5_kernel<true><<<NL * NW, BLKT, 0, stream>>>(x, Wg, Ug, bg, dWg, pw, out);
        reduce_kernel<<<T, 512, 0, stream>>>(pw, dbv, out);
    } else {
        init_out_kernel<<<(out_size + 255) / 256, 256, 0, stream>>>(dbv, out, out_size);
        lstm_mfma5_kernel<false><<<NL * NW, BLKT, 0, stream>>>(x, Wg, Ug, bg, dWg, nullptr, out);
    }
}

// Round 10
// 229.975 us; speedup vs baseline: 1.3268x; 1.0008x over previous
//
#include <hip/hip_runtime.h>
#include <math.h>

// Problem constants: N=200 LSTMs, B=100, T=256, D=5 (io), H=20 (units)
constexpr int NL = 200;
constexpr int B  = 100;
constexpr int T  = 256;
constexpr int D  = 5;
constexpr int H  = 20;
constexpr int NW = 7;      // 16-batch groups per LSTM; 7*16=112 >= 100
constexpr int KP = 40;     // bcol row pitch in bf16 (80 B)
constexpr int NWAVE = 5;   // wave m computes recurrence tile Mt=m
constexpr int BLKT  = 64 * NWAVE;   // 320 threads

// k-axis layout of the per-batch data column (K=32):
//   k 0..23  = h region, k = g*6 + mt  (hh = mt*4 + g; mt==5 -> always 0)
//   k 24..28 = x_t[0..4]   (one aligned 16B store per step, k24..31)
//   k 30     = 1.0 (bias slot), k 29,31 = 0
constexpr int KX = 24;

typedef float  f32x4  __attribute__((ext_vector_type(4)));
typedef short  bf16x8 __attribute__((ext_vector_type(8)));

__device__ __forceinline__ float rcpf(float x) { return __builtin_amdgcn_rcpf(x); }

#if __has_builtin(__builtin_amdgcn_exp2f)
__device__ __forceinline__ float exp2fast(float x) { return __builtin_amdgcn_exp2f(x); }
#else
__device__ __forceinline__ float exp2fast(float x) { return __expf(x * 0.6931471805599453f); }
#endif

// fp32 -> bf16 bits, round-to-nearest-even
__device__ __forceinline__ unsigned short f2bf(float f) {
    union { float f; unsigned u; } v; v.f = f;
    unsigned r = v.u + 0x7fffu + ((v.u >> 16) & 1u);
    return (unsigned short)(r >> 16);
}

// LDS-only block barrier: does NOT drain vmcnt, so global stores (dense
// partials) and global loads (x prefetch) stay in flight across steps.
// __syncthreads would emit s_waitcnt vmcnt(0) lgkmcnt(0) and stall ~300-500cy
// per step on the dense-store retirement.
__device__ __forceinline__ void block_sync_lds() {
    asm volatile("s_waitcnt lgkmcnt(0)" ::: "memory");
    __builtin_amdgcn_s_barrier();
}

constexpr float NLOG2E = -1.4426950408889634f;
constexpr float TLOG2E = 2.8853900817779268f;   // 2*log2(e)

__global__ __launch_bounds__(256) void init_out_kernel(const float* __restrict__ dense_b,
                                                       float* __restrict__ out, int n) {
    int i = blockIdx.x * 256 + threadIdx.x;
    if (i < n) out[i] = dense_b[i % D];
}

// One block per (lstm n, 16-batch group w); 5 waves per block.
// Wave m: ONE mfma_f32_16x16x32_bf16 (gate tile Mt=m; bias folded into k=30
// column, scale -log2e / +2log2e folded into A) + ONE activation chain per
// step; lane (c16,g4) owns (hh = 4m+g4, b = 16w+c16) and writes ONE bf16 h.
// Wave 1 extra: dense MFMA (A = dense_W^T rows d=0..4) pipelined one step
// behind. Wave 0 lanes<16 extra: stage x into the other buffer.
// bcol double-buffered; ONE lgkm-only barrier per step.
template<bool USE_WS>
__global__ __attribute__((amdgpu_flat_work_group_size(BLKT, BLKT)))
void lstm_mfma5_kernel(
    const float* __restrict__ x,    // [B][T][D]
    const float* __restrict__ Wg,   // [N][D][4H]
    const float* __restrict__ Ug,   // [N][H][4H]
    const float* __restrict__ bg,   // [N][4H]
    const float* __restrict__ dWg,  // [N*H][D]
    float* __restrict__ pw,         // [N][T][D][B] partials (USE_WS)
    float* __restrict__ out)        // [B][T][D] (atomic fallback)
{
    const int blk = blockIdx.x;            // 0..1399
    const int n   = blk / NW;
    const int w   = blk % NW;
    const int tid = threadIdx.x;
    const int wid = tid >> 6;              // 0..4 = Mt of this wave
    const int l   = tid & 63;
    const int c16 = l & 15;
    const int g4  = l >> 4;

    __shared__ __align__(16) short bcol[2][16][KP];   // double-buffered

    for (int i = tid; i < 2 * 16 * KP / 2; i += BLKT)
        ((int*)&bcol[0][0][0])[i] = 0;

    const float* Un = Ug  + (size_t)n * H * 4 * H;
    const float* Wn = Wg  + (size_t)n * D * 4 * H;
    const float* bn = bg  + (size_t)n * 4 * H;
    const float* dn = dWg + (size_t)n * H * D;

    // ---- recurrence A fragment for this wave (Mt = wid), k = 8*g4 + j ----
    const int gateA = c16 & 3;
    const int hA4   = c16 >> 2;
    const float sA  = (gateA == 2) ? TLOG2E : NLOG2E;
    const int colA  = gateA * H + (wid * 4 + hA4);   // column in [*,4H] weights
    bf16x8 afrag;
    #pragma unroll
    for (int j = 0; j < 8; ++j) {
        const int k = 8 * g4 + j;
        float v = 0.0f;
        if (k < KX) {                          // h region: k = g*6 + mt
            const int mt = k % 6, gg = k / 6;
            if (mt < 5) v = Un[(mt * 4 + gg) * 4 * H + colA];
        } else if (k < KX + D) {               // x region
            v = Wn[(k - KX) * 4 * H + colA];
        } else if (k == 30) {                  // bias slot
            v = bn[colA];
        }
        afrag[j] = (short)f2bf(sA * v);
    }
    // ---- dense A fragment (wave 1 only): rows 0..4 = d, h region only ----
    bf16x8 afrag_d = {};
    if (wid == 1) {
        #pragma unroll
        for (int j = 0; j < 8; ++j) {
            const int k = 8 * g4 + j;
            float v = 0.0f;
            if (c16 < D && k < KX) {
                const int mt = k % 6, gg = k / 6;
                if (mt < 5) v = dn[(mt * 4 + gg) * D + c16];
            }
            afrag_d[j] = (short)f2bf(v);
        }
    }

    const int  bgl    = w * 16 + c16;          // global batch of this lane-col
    const bool bvalid = bgl < B;
    const float* xp   = x + (size_t)(bvalid ? bgl : 0) * T * D;
    float* pwn = USE_WS ? (pw + (size_t)n * T * (D * B))
                        : (out + ((size_t)bgl * T) * D);

    __syncthreads();                            // zero-init visible

    // prologue: wave0 stages x(0) into buf 0; preloads x(1)
    float xn[D];
    if (wid == 0 && l < 16) {
        bf16x8 xb;
        #pragma unroll
        for (int d = 0; d < D; ++d) xb[d] = (short)f2bf(xp[d]);
        xb[5] = 0; xb[6] = (short)0x3F80; xb[7] = 0;      // bias = 1.0
        *(bf16x8*)&bcol[0][c16][KX] = xb;
        const float* x1 = xp + (size_t)((T > 1) ? 1 : 0) * D;
        #pragma unroll
        for (int d = 0; d < D; ++d) xn[d] = x1[d];
    }
    __syncthreads();

    float cst = 0.0f;
    const f32x4 zero4 = {0.0f, 0.0f, 0.0f, 0.0f};
    int p = 0;

    for (int t = 0; t < T; ++t) {
        // buf[p] holds h(t-1) and x(t)
        const bf16x8 bfrag = *(const bf16x8*)&bcol[p][c16][8 * g4];  // ds_read_b128

        if (wid == 1) {
            // dense for step t-1 (uses h(t-1) in bfrag)
            const f32x4 accd = __builtin_amdgcn_mfma_f32_16x16x32_bf16(
                afrag_d, bfrag, zero4, 0, 0, 0);
            if (t > 0 && bvalid) {
                #pragma unroll
                for (int reg = 0; reg < 4; ++reg) {
                    const int d = g4 * 4 + reg;            // output row = d
                    if (d < D) {
                        if (USE_WS)
                            pwn[(size_t)(t - 1) * (D * B) + d * B + bgl] = accd[reg];
                        else
                            atomicAdd(&pwn[(size_t)(t - 1) * D + d], accd[reg]);
                    }
                }
            }
        }

        // recurrence tile Mt = wid
        const f32x4 acc = __builtin_amdgcn_mfma_f32_16x16x32_bf16(
            afrag, bfrag, zero4, 0, 0, 0);
        // acc = {-z_i, -z_f, 2*z_g, -z_o} * log2e  (bias via k=30)
        const float iv = rcpf(1.0f + exp2fast(acc[0]));
        const float fv = rcpf(1.0f + exp2fast(acc[1]));
        const float gv = fmaf(-2.0f, rcpf(exp2fast(acc[2]) + 1.0f), 1.0f);
        const float ov = rcpf(1.0f + exp2fast(acc[3]));
        cst = fmaf(fv, cst, iv * gv);
        const float th = fmaf(-2.0f, rcpf(exp2fast(TLOG2E * cst) + 1.0f), 1.0f);
        const float hv = ov * th;

        // h(t): one bf16 store at k = g4*6 + wid into the other buffer
        bcol[p ^ 1][c16][g4 * 6 + wid] = (short)f2bf(hv);

        // wave0: stage x(t+1) into the other buffer; load x(t+2)
        if (wid == 0 && l < 16) {
            bf16x8 xb;
            #pragma unroll
            for (int d = 0; d < D; ++d) xb[d] = (short)f2bf(xn[d]);
            xb[5] = 0; xb[6] = (short)0x3F80; xb[7] = 0;
            *(bf16x8*)&bcol[p ^ 1][c16][KX] = xb;
            const float* x2 = xp + (size_t)((t + 2 < T) ? t + 2 : T - 1) * D;
            #pragma unroll
            for (int d = 0; d < D; ++d) xn[d] = x2[d];
        }

        block_sync_lds();      // LDS-only barrier: global stores stay in flight
        p ^= 1;
    }

    // final dense: buf[p] holds h(T-1)
    if (wid == 1) {
        const bf16x8 bfrag = *(const bf16x8*)&bcol[p][c16][8 * g4];
        const f32x4 accd = __builtin_amdgcn_mfma_f32_16x16x32_bf16(
            afrag_d, bfrag, zero4, 0, 0, 0);
        if (bvalid) {
            #pragma unroll
            for (int reg = 0; reg < 4; ++reg) {
                const int d = g4 * 4 + reg;
                if (d < D) {
                    if (USE_WS)
                        pwn[(size_t)(T - 1) * (D * B) + d * B + bgl] = accd[reg];
                    else
                        atomicAdd(&pwn[(size_t)(T - 1) * D + d], accd[reg]);
                }
            }
        }
    }
}

// out[b][t][d] = dense_b[d] + sum_n pw[n][t][d][b]  (coalesced reads)
__global__ __launch_bounds__(512) void reduce_kernel(
    const float* __restrict__ pw, const float* __restrict__ dense_b,
    float* __restrict__ out)
{
    const int t    = blockIdx.x;
    const int flat = threadIdx.x;              // d*B + b, 0..499
    if (flat >= B * D) return;
    const int d = flat / B;
    const int b = flat % B;
    const float* p = pw + (size_t)t * (D * B) + flat;
    constexpr size_t stride = (size_t)T * D * B;
    float a0 = 0.0f, a1 = 0.0f;
    #pragma unroll 10
    for (int n = 0; n < NL; n += 2) {
        a0 += p[(size_t)n * stride];
        a1 += p[(size_t)(n + 1) * stride];
    }
    out[((size_t)b * T + t) * D + d] = a0 + a1 + dense_b[d];
}

extern "C" void kernel_launch(void* const* d_in, const int* in_sizes, int n_in,
                              void* d_out, int out_size, void* d_ws, size_t ws_size,
                              hipStream_t stream) {
    const float* x   = (const float*)d_in[0];
    const float* Wg  = (const float*)d_in[1];
    const float* Ug  = (const float*)d_in[2];
    const float* bg  = (const float*)d_in[3];
    const float* dWg = (const float*)d_in[4];
    const float* dbv = (const float*)d_in[5];
    float* out = (float*)d_out;

    const size_t need = (size_t)NL * T * D * B * sizeof(float);   // 102.4 MB
    if (ws_size >= need) {
        float* pw = (float*)d_ws;
        lstm_mfma5_kernel<true><<<NL * NW, BLKT, 0, stream>>>(x, Wg, Ug, bg, dWg, pw, out);
        reduce_kernel<<<T, 512, 0, stream>>>(pw, dbv, out);
    } else {
        init_out_kernel<<<(out_size + 255) / 256, 256, 0, stream>>>(dbv, out, out_size);
        lstm_mfma5_kernel<false><<<NL * NW, BLKT, 0, stream>>>(x, Wg, Ug, bg, dWg, nullptr, out);
    }
}